// Round 1
// baseline (114.725 us; speedup 1.0000x reference)
//
#include <hip/hip_runtime.h>

#define IMG_H 200
#define IMG_W 200
#define VOLD  256          // volume is 256^3, strides: x<<16, y<<8, z
#define KPH   8            // threads (phases) per pixel

__global__ __launch_bounds__(256) void drr_kernel(
    const float* __restrict__ vol,
    const float* __restrict__ kinv,   // [3][3]
    const float* __restrict__ rt,     // [4][4]
    const float* __restrict__ sddp,   // [1]
    const float* __restrict__ aff,    // [4][4]
    const int*   __restrict__ nsp,    // [1]
    float*       __restrict__ out)    // [H*W]
{
    const int tid   = blockIdx.x * blockDim.x + threadIdx.x;
    const int p     = tid >> 3;       // pixel index
    const int phase = tid & (KPH - 1);
    if (p >= IMG_H * IMG_W) return;

    const int   N     = nsp[0];
    const float sdd   = sddp[0];
    const float invN1 = 1.0f / (float)(N - 1);

    const float u = (float)(p % IMG_W);
    const float v = (float)(p / IMG_W);

    // tgt_cam = K^-1 * (u,v,1) * sdd
    const float tcx = (kinv[0]*u + kinv[1]*v + kinv[2]) * sdd;
    const float tcy = (kinv[3]*u + kinv[4]*v + kinv[5]) * sdd;
    const float tcz = (kinv[6]*u + kinv[7]*v + kinv[8]) * sdd;

    // ray = R * tgt_cam ; src = t
    const float rx = rt[0]*tcx + rt[1]*tcy + rt[2]*tcz;
    const float ry = rt[4]*tcx + rt[5]*tcy + rt[6]*tcz;
    const float rz = rt[8]*tcx + rt[9]*tcy + rt[10]*tcz;
    const float sx = rt[3], sy = rt[7], sz = rt[11];

    // voxel-space: vox(t) = base + t * dir
    const float bx = aff[0]*sx + aff[1]*sy + aff[2]*sz  + aff[3];
    const float by = aff[4]*sx + aff[5]*sy + aff[6]*sz  + aff[7];
    const float bz = aff[8]*sx + aff[9]*sy + aff[10]*sz + aff[11];
    const float dx = aff[0]*rx + aff[1]*ry + aff[2]*rz;
    const float dy = aff[4]*rx + aff[5]*ry + aff[6]*rz;
    const float dz = aff[8]*rx + aff[9]*ry + aff[10]*rz;

    // ---- ray/box culling: sample is nonzero only if all coords in (-1, 256)
    float t0 = 0.0f, t1 = 1.0f;
    {
        const float lo = -1.0f, hi = (float)VOLD;
        #pragma unroll
        for (int d = 0; d < 3; ++d) {
            const float b = (d == 0) ? bx : (d == 1) ? by : bz;
            const float dd = (d == 0) ? dx : (d == 1) ? dy : dz;
            if (fabsf(dd) > 1e-20f) {
                const float ta = (lo - b) / dd;
                const float tb = (hi - b) / dd;
                t0 = fmaxf(t0, fminf(ta, tb));
                t1 = fminf(t1, fmaxf(ta, tb));
            } else if (b <= lo || b >= hi) {
                t0 = 1.0f; t1 = -1.0f;   // empty
            }
        }
    }
    int s_lo = 0, s_hi = -1;
    if (t0 <= t1) {
        s_lo = (int)floorf(t0 * (float)(N - 1)) - 1;
        s_hi = (int)ceilf (t1 * (float)(N - 1)) + 1;
        s_lo = max(s_lo, 0);
        s_hi = min(s_hi, N - 1);
    }

    float acc = 0.0f;
    for (int s = s_lo + phase; s <= s_hi; s += KPH) {
        const float t = (float)s * invN1;
        const float x = fmaf(t, dx, bx);
        const float y = fmaf(t, dy, by);
        const float z = fmaf(t, dz, bz);
        const float fx = floorf(x), fy = floorf(y), fz = floorf(z);
        const int ix = (int)fx, iy = (int)fy, iz = (int)fz;
        const float wx = x - fx, wy = y - fy, wz = z - fz;

        float c000, c001, c010, c011, c100, c101, c110, c111;
        if ((unsigned)ix < 255u && (unsigned)iy < 255u && (unsigned)iz < 255u) {
            // fully interior: all 8 corners valid
            const float* pb = vol + ((ix << 16) + (iy << 8) + iz);
            c000 = pb[0];         c001 = pb[1];
            c010 = pb[256];       c011 = pb[257];
            c100 = pb[65536];     c101 = pb[65537];
            c110 = pb[65536+256]; c111 = pb[65536+257];
        } else {
            const bool x0 = (unsigned)ix       < 256u;
            const bool x1 = (unsigned)(ix + 1) < 256u;
            const bool y0 = (unsigned)iy       < 256u;
            const bool y1 = (unsigned)(iy + 1) < 256u;
            const bool z0 = (unsigned)iz       < 256u;
            const bool z1 = (unsigned)(iz + 1) < 256u;
            const int bx0 = ix << 16, bx1 = (ix + 1) << 16;
            const int by0 = iy << 8,  by1 = (iy + 1) << 8;
            c000 = (x0 && y0 && z0) ? vol[bx0 + by0 + iz]     : 0.0f;
            c001 = (x0 && y0 && z1) ? vol[bx0 + by0 + iz + 1] : 0.0f;
            c010 = (x0 && y1 && z0) ? vol[bx0 + by1 + iz]     : 0.0f;
            c011 = (x0 && y1 && z1) ? vol[bx0 + by1 + iz + 1] : 0.0f;
            c100 = (x1 && y0 && z0) ? vol[bx1 + by0 + iz]     : 0.0f;
            c101 = (x1 && y0 && z1) ? vol[bx1 + by0 + iz + 1] : 0.0f;
            c110 = (x1 && y1 && z0) ? vol[bx1 + by1 + iz]     : 0.0f;
            c111 = (x1 && y1 && z1) ? vol[bx1 + by1 + iz + 1] : 0.0f;
        }

        const float c00 = fmaf(wz, c001 - c000, c000);
        const float c01 = fmaf(wz, c011 - c010, c010);
        const float c10 = fmaf(wz, c101 - c100, c100);
        const float c11 = fmaf(wz, c111 - c110, c110);
        const float c0  = fmaf(wy, c01 - c00, c00);
        const float c1  = fmaf(wy, c11 - c10, c10);
        acc += fmaf(wx, c1 - c0, c0);
    }

    // reduce the 8 phases of this pixel (contiguous lanes)
    acc += __shfl_down(acc, 4, KPH);
    acc += __shfl_down(acc, 2, KPH);
    acc += __shfl_down(acc, 1, KPH);

    if (phase == 0) {
        const float step = sqrtf(rx*rx + ry*ry + rz*rz) * invN1;
        out[p] = acc * step;
    }
}

extern "C" void kernel_launch(void* const* d_in, const int* in_sizes, int n_in,
                              void* d_out, int out_size, void* d_ws, size_t ws_size,
                              hipStream_t stream) {
    const float* vol  = (const float*)d_in[0];
    const float* kinv = (const float*)d_in[1];
    const float* rt   = (const float*)d_in[2];
    const float* sdd  = (const float*)d_in[3];
    const float* aff  = (const float*)d_in[4];
    const int*   nsp  = (const int*)d_in[5];
    float* out = (float*)d_out;

    const int threads = IMG_H * IMG_W * KPH;   // 320000
    dim3 block(256);
    dim3 grid((threads + 255) / 256);          // 1250
    drr_kernel<<<grid, block, 0, stream>>>(vol, kinv, rt, sdd, aff, nsp, out);
}

// Round 2
// 111.025 us; speedup vs baseline: 1.0333x; 1.0333x over previous
//
#include <hip/hip_runtime.h>

#define IMG_H 200
#define IMG_W 200
#define VOLD  256          // volume is 256^3, strides: x<<16, y<<8, z
#define KPH   16           // threads (phases) per pixel

__global__ __launch_bounds__(256) void drr_kernel(
    const float* __restrict__ vol,
    const float* __restrict__ kinv,   // [3][3]
    const float* __restrict__ rt,     // [4][4]
    const float* __restrict__ sddp,   // [1]
    const float* __restrict__ aff,    // [4][4]
    const int*   __restrict__ nsp,    // [1]
    float*       __restrict__ out)    // [H*W]
{
    const int tid   = blockIdx.x * blockDim.x + threadIdx.x;
    const int p     = tid / KPH;      // pixel index
    const int phase = tid & (KPH - 1);
    if (p >= IMG_H * IMG_W) return;

    const int   N     = nsp[0];
    const float sdd   = sddp[0];
    const float invN1 = 1.0f / (float)(N - 1);

    const float u = (float)(p % IMG_W);
    const float v = (float)(p / IMG_W);

    // tgt_cam = K^-1 * (u,v,1) * sdd
    const float tcx = (kinv[0]*u + kinv[1]*v + kinv[2]) * sdd;
    const float tcy = (kinv[3]*u + kinv[4]*v + kinv[5]) * sdd;
    const float tcz = (kinv[6]*u + kinv[7]*v + kinv[8]) * sdd;

    // ray = R * tgt_cam ; src = t
    const float rx = rt[0]*tcx + rt[1]*tcy + rt[2]*tcz;
    const float ry = rt[4]*tcx + rt[5]*tcy + rt[6]*tcz;
    const float rz = rt[8]*tcx + rt[9]*tcy + rt[10]*tcz;
    const float sx = rt[3], sy = rt[7], sz = rt[11];

    // voxel-space: vox(t) = base + t * dir
    const float bx = aff[0]*sx + aff[1]*sy + aff[2]*sz  + aff[3];
    const float by = aff[4]*sx + aff[5]*sy + aff[6]*sz  + aff[7];
    const float bz = aff[8]*sx + aff[9]*sy + aff[10]*sz + aff[11];
    const float dx = aff[0]*rx + aff[1]*ry + aff[2]*rz;
    const float dy = aff[4]*ry ? (aff[4]*rx + aff[5]*ry + aff[6]*rz)
                               : (aff[4]*rx + aff[5]*ry + aff[6]*rz); // keep simple form
    const float dy2 = aff[4]*rx + aff[5]*ry + aff[6]*rz;
    const float dz = aff[8]*rx + aff[9]*ry + aff[10]*rz;
    const float DY = dy2; (void)dy;

    // ---- ray/box culling: sample is nonzero only if all coords in (-1, 256)
    float t0 = 0.0f, t1 = 1.0f;
    {
        const float lo = -1.0f, hi = (float)VOLD;
        const float bs[3] = {bx, by, bz};
        const float ds[3] = {dx, DY, dz};
        #pragma unroll
        for (int d = 0; d < 3; ++d) {
            const float b  = bs[d];
            const float dd = ds[d];
            if (fabsf(dd) > 1e-20f) {
                const float ta = (lo - b) / dd;
                const float tb = (hi - b) / dd;
                t0 = fmaxf(t0, fminf(ta, tb));
                t1 = fminf(t1, fmaxf(ta, tb));
            } else if (b <= lo || b >= hi) {
                t0 = 1.0f; t1 = -1.0f;   // empty
            }
        }
    }
    int s_lo = 0, s_hi = -1;
    if (t0 <= t1) {
        s_lo = (int)floorf(t0 * (float)(N - 1)) - 1;
        s_hi = (int)ceilf (t1 * (float)(N - 1)) + 1;
        s_lo = max(s_lo, 0);
        s_hi = min(s_hi, N - 1);
    }

    float acc = 0.0f;
    #pragma unroll 2
    for (int s = s_lo + phase; s <= s_hi; s += KPH) {
        const float t = (float)s * invN1;
        const float x = fmaf(t, dx, bx);
        const float y = fmaf(t, DY, by);
        const float z = fmaf(t, dz, bz);
        const float fx = floorf(x), fy = floorf(y), fz = floorf(z);
        const int ix = (int)fx, iy = (int)fy, iz = (int)fz;
        const float wx = x - fx, wy = y - fy, wz = z - fz;

        float c000, c001, c010, c011, c100, c101, c110, c111;
        if ((unsigned)ix < 255u && (unsigned)iy < 255u && (unsigned)iz < 255u) {
            // fully interior: all 8 corners valid
            const float* pb = vol + ((ix << 16) + (iy << 8) + iz);
            c000 = pb[0];         c001 = pb[1];
            c010 = pb[256];       c011 = pb[257];
            c100 = pb[65536];     c101 = pb[65537];
            c110 = pb[65536+256]; c111 = pb[65536+257];
        } else {
            const bool x0 = (unsigned)ix       < 256u;
            const bool x1 = (unsigned)(ix + 1) < 256u;
            const bool y0 = (unsigned)iy       < 256u;
            const bool y1 = (unsigned)(iy + 1) < 256u;
            const bool z0 = (unsigned)iz       < 256u;
            const bool z1 = (unsigned)(iz + 1) < 256u;
            const int bx0 = ix << 16, bx1 = (ix + 1) << 16;
            const int by0 = iy << 8,  by1 = (iy + 1) << 8;
            c000 = (x0 && y0 && z0) ? vol[bx0 + by0 + iz]     : 0.0f;
            c001 = (x0 && y0 && z1) ? vol[bx0 + by0 + iz + 1] : 0.0f;
            c010 = (x0 && y1 && z0) ? vol[bx0 + by1 + iz]     : 0.0f;
            c011 = (x0 && y1 && z1) ? vol[bx0 + by1 + iz + 1] : 0.0f;
            c100 = (x1 && y0 && z0) ? vol[bx1 + by0 + iz]     : 0.0f;
            c101 = (x1 && y0 && z1) ? vol[bx1 + by0 + iz + 1] : 0.0f;
            c110 = (x1 && y1 && z0) ? vol[bx1 + by1 + iz]     : 0.0f;
            c111 = (x1 && y1 && z1) ? vol[bx1 + by1 + iz + 1] : 0.0f;
        }

        const float c00 = fmaf(wz, c001 - c000, c000);
        const float c01 = fmaf(wz, c011 - c010, c010);
        const float c10 = fmaf(wz, c101 - c100, c100);
        const float c11 = fmaf(wz, c111 - c110, c110);
        const float c0  = fmaf(wy, c01 - c00, c00);
        const float c1  = fmaf(wy, c11 - c10, c10);
        acc += fmaf(wx, c1 - c0, c0);
    }

    // reduce the 16 phases of this pixel (contiguous lanes)
    acc += __shfl_down(acc, 8, KPH);
    acc += __shfl_down(acc, 4, KPH);
    acc += __shfl_down(acc, 2, KPH);
    acc += __shfl_down(acc, 1, KPH);

    if (phase == 0) {
        const float step = sqrtf(rx*rx + ry*ry + rz*rz) * invN1;
        out[p] = acc * step;
    }
}

extern "C" void kernel_launch(void* const* d_in, const int* in_sizes, int n_in,
                              void* d_out, int out_size, void* d_ws, size_t ws_size,
                              hipStream_t stream) {
    const float* vol  = (const float*)d_in[0];
    const float* kinv = (const float*)d_in[1];
    const float* rt   = (const float*)d_in[2];
    const float* sdd  = (const float*)d_in[3];
    const float* aff  = (const float*)d_in[4];
    const int*   nsp  = (const int*)d_in[5];
    float* out = (float*)d_out;

    const long long threads = (long long)IMG_H * IMG_W * KPH;   // 640000
    dim3 block(256);
    dim3 grid((unsigned)((threads + 255) / 256));               // 2500
    drr_kernel<<<grid, block, 0, stream>>>(vol, kinv, rt, sdd, aff, nsp, out);
}